// Round 6
// baseline (93.426 us; speedup 1.0000x reference)
//
#include <hip/hip_runtime.h>
#include <hip/hip_bf16.h>

typedef __attribute__((ext_vector_type(8))) short short8;
typedef __attribute__((ext_vector_type(4))) float f32x4;

#define B_  8
#define L_  2048
#define T_  512
#define DH_ 1024
#define DG_ 768
#define P_  256

__device__ __forceinline__ short f2bf(float x) {
    union { float f; unsigned u; } v; v.f = x;
    unsigned r = v.u + 0x7fffu + ((v.u >> 16) & 1u);
    return (short)(r >> 16);
}

typedef __attribute__((address_space(1))) const void av1_t;
typedef __attribute__((address_space(3))) void av3_t;
__device__ __forceinline__ void gl16(const void* g, void* l) {
    __builtin_amdgcn_global_load_lds((av1_t*)g, (av3_t*)l, 16, 0, 0);
}

// ---------------- shared GEMM body ----------------
// C[M,N] = A[M,K] * B[N,K]^T, 4 waves (2x2), BK=64, gl16 staging for bf16,
// XOR-swizzled LDS. As: BM*64 shorts, Bs: BN*64 shorts, invL: BM floats.
// EPI: 1 = bf16 C*cscale
//      2 = QK: e=mask?0:exp(C); bf16 e + per-row partial sums psum[row][32]
//      3 = PV: f32 C * (1/sum(psum row))
template<int BM, int BN, bool AF32, int EPI>
__device__ __forceinline__ void gemm_body(
    const void* __restrict__ Ap, const short* __restrict__ Bp,
    void* __restrict__ Cp, int M, int N, int K, long sA, long sB, long sC,
    float cscale, const unsigned char* __restrict__ mask,
    float* __restrict__ psum, int bx, int by, int b,
    short* As, short* Bs, float* invL)
{
    constexpr int WM = BM / 2, WN = BN / 2, FM = WM / 16, FN = WN / 16;
    const int m0 = by * BM, n0 = bx * BN;

    const int t = threadIdx.x, w = t >> 6, l = t & 63;
    const int wm = w >> 1, wn = w & 1, rl = l & 15, kg = l >> 4;

    const int srow = t >> 3;
    const int schunk = t & 7;
    const int gchunk = schunk ^ (srow & 7);

    const short* Bg0 = Bp + (long)b * sB + (long)(n0 + srow) * K + gchunk * 8;
    char* AsP = (char*)As + t * 16;
    char* BsP = (char*)Bs + t * 16;

    const int ch0 = ((0 | kg) ^ (rl & 7)) * 16;
    const int ch1 = ((4 | kg) ^ (rl & 7)) * 16;

    if constexpr (EPI == 3) {   // denominators: overlap with first staging
        if (t < BM) {
            const float* pp = psum + ((long)b * M + m0 + t) * 32;
            float s = 0.f;
            #pragma unroll
            for (int j = 0; j < 32; j++) s += pp[j];
            invL[t] = 1.0f / s;
        }
    }

    f32x4 acc[FM][FN];
    #pragma unroll
    for (int mi = 0; mi < FM; mi++)
        #pragma unroll
        for (int ni = 0; ni < FN; ni++)
            acc[mi][ni] = (f32x4){0.f, 0.f, 0.f, 0.f};

    for (int k0 = 0; k0 < K; k0 += 64) {
        if (AF32) {
            #pragma unroll
            for (int j = 0; j < BM / 32; j++) {
                const float* ag = (const float*)Ap + (long)b * sA +
                                  (long)(m0 + j * 32 + srow) * K + k0 + schunk * 8;
                float4 v0 = *(const float4*)ag;
                float4 v1 = *(const float4*)(ag + 4);
                short8 sv;
                sv[0]=f2bf(v0.x); sv[1]=f2bf(v0.y); sv[2]=f2bf(v0.z); sv[3]=f2bf(v0.w);
                sv[4]=f2bf(v1.x); sv[5]=f2bf(v1.y); sv[6]=f2bf(v1.z); sv[7]=f2bf(v1.w);
                *(short8*)&As[(j * 32 + srow) * 64 + (schunk ^ (srow & 7)) * 8] = sv;
            }
        } else {
            const short* Ag0 = (const short*)Ap + (long)b * sA +
                               (long)(m0 + srow) * K + k0 + gchunk * 8;
            #pragma unroll
            for (int j = 0; j < BM / 32; j++)
                gl16(Ag0 + (long)j * 32 * K, AsP + j * 4096);
        }
        #pragma unroll
        for (int j = 0; j < BN / 32; j++)
            gl16(Bg0 + k0 + (long)j * 32 * K, BsP + j * 4096);
        __syncthreads();

        #pragma unroll
        for (int kh = 0; kh < 2; kh++) {
            const int ch = kh ? ch1 : ch0;
            short8 a[FM], bb[FN];
            #pragma unroll
            for (int mi = 0; mi < FM; mi++)
                a[mi] = *(short8*)((char*)&As[(wm * WM + mi * 16 + rl) * 64] + ch);
            #pragma unroll
            for (int ni = 0; ni < FN; ni++)
                bb[ni] = *(short8*)((char*)&Bs[(wn * WN + ni * 16 + rl) * 64] + ch);
            #pragma unroll
            for (int mi = 0; mi < FM; mi++)
                #pragma unroll
                for (int ni = 0; ni < FN; ni++)
                    acc[mi][ni] = __builtin_amdgcn_mfma_f32_16x16x32_bf16(
                        a[mi], bb[ni], acc[mi][ni], 0, 0, 0);
        }
        __syncthreads();
    }

    const int rowb = m0 + wm * WM + kg * 4;

    if constexpr (EPI == 2) {
        float* psL = (float*)As;  // [2][BM]
        float pr[FM][4];
        #pragma unroll
        for (int mi = 0; mi < FM; mi++)
            #pragma unroll
            for (int i = 0; i < 4; i++) pr[mi][i] = 0.f;
        #pragma unroll
        for (int mi = 0; mi < FM; mi++)
            #pragma unroll
            for (int ni = 0; ni < FN; ni++) {
                const int n = n0 + wn * WN + ni * 16 + rl;
                const bool mk = mask[(long)b * N + n] != 0;
                #pragma unroll
                for (int i = 0; i < 4; i++) {
                    const float e = mk ? 0.f : __expf(acc[mi][ni][i]);
                    ((short*)Cp)[(long)b * sC + (long)(rowb + mi * 16 + i) * N + n] = f2bf(e);
                    pr[mi][i] += e;
                }
            }
        #pragma unroll
        for (int off = 1; off < 16; off <<= 1)
            #pragma unroll
            for (int mi = 0; mi < FM; mi++)
                #pragma unroll
                for (int i = 0; i < 4; i++)
                    pr[mi][i] += __shfl_xor(pr[mi][i], off);
        if (rl == 0) {
            #pragma unroll
            for (int mi = 0; mi < FM; mi++)
                #pragma unroll
                for (int i = 0; i < 4; i++)
                    psL[wn * BM + wm * WM + mi * 16 + kg * 4 + i] = pr[mi][i];
        }
        __syncthreads();
        if (t < BM)
            psum[((long)b * M + m0 + t) * 32 + bx] = psL[t] + psL[BM + t];
        return;
    }

    #pragma unroll
    for (int mi = 0; mi < FM; mi++)
        #pragma unroll
        for (int ni = 0; ni < FN; ni++) {
            const int n = n0 + wn * WN + ni * 16 + rl;
            #pragma unroll
            for (int i = 0; i < 4; i++) {
                const long idx = (long)b * sC + (long)(rowb + mi * 16 + i) * N + n;
                if constexpr (EPI == 1)
                    ((short*)Cp)[idx] = f2bf(acc[mi][ni][i] * cscale);
                else  // EPI == 3
                    ((float*)Cp)[idx] = acc[mi][ni][i] *
                                        invL[wm * WM + mi * 16 + kg * 4 + i];
            }
        }
}

// ---------------- transpose bodies ----------------
__device__ __forceinline__ void transpose32_body(
    const float* __restrict__ s, short* __restrict__ d,
    int R, int C, int r0, int c0, float* tile /*32x33*/)
{
    const int x = threadIdx.x & 31, y = threadIdx.x >> 5;
    #pragma unroll
    for (int i = 0; i < 32; i += 8)
        tile[(y + i) * 33 + x] = s[(long)(r0 + y + i) * C + (c0 + x)];
    __syncthreads();
    #pragma unroll
    for (int i = 0; i < 32; i += 8)
        d[(long)(c0 + y + i) * R + (r0 + x)] = f2bf(tile[x * 33 + y + i]);
}

__device__ __forceinline__ void transpose64_body(
    const float* __restrict__ s, short* __restrict__ d,
    int R, int C, int r0, int c0, float* tile /*64x65*/)
{
    const int x = threadIdx.x & 63, y = threadIdx.x >> 6;
    #pragma unroll
    for (int i = 0; i < 64; i += 4)
        tile[(y + i) * 65 + x] = s[(long)(r0 + y + i) * C + (c0 + x)];
    __syncthreads();
    #pragma unroll
    for (int i = 0; i < 64; i += 4)
        d[(long)(c0 + y + i) * R + (r0 + x)] = f2bf(tile[x * 65 + y + i]);
}

// ---------------- kernels ----------------
// Phase A: both weight transposes. blocks: Wk 32x8=256, Wq 24x8=192.
__global__ __launch_bounds__(256) void k_weights(
    const float* __restrict__ Wk, short* __restrict__ WkT,
    const float* __restrict__ Wq, short* __restrict__ WqT)
{
    __shared__ float tile[32 * 33];
    const int f = blockIdx.x;
    if (f < 256) {
        transpose32_body(Wk, WkT, DH_, P_, (f & 31) * 32, (f >> 5) * 32, tile);
    } else {
        const int f2 = f - 256;
        transpose32_body(Wq, WqT, DG_, P_, (f2 % 24) * 32, (f2 / 24) * 32, tile);
    }
}

// Phase B: K-proj (128 blocks, 128x256 tile) + Q-proj (32) + Ht transpose (4096).
// GEMM roles first in block order -> they start immediately; BW-bound
// transpose blocks backfill and hide GEMM staging latency (m114 co-schedule).
__global__ __launch_bounds__(256) void k_phaseB(
    const float* __restrict__ H, const float* __restrict__ G,
    const short* __restrict__ WkT, const short* __restrict__ WqT,
    short* __restrict__ Kb, short* __restrict__ Qb, short* __restrict__ Ht)
{
    __shared__ __align__(16) char smem[16384 + 32768 + 512];
    const int f = blockIdx.x;
    if (f < 128) {                      // K-proj: 16 by x 8 b
        gemm_body<128, 256, true, 1>(
            H, WkT, Kb, L_, P_, DH_, (long)L_ * DH_, 0, (long)L_ * P_,
            1.0f, nullptr, nullptr, 0, f & 15, f >> 4,
            (short*)smem, (short*)(smem + 16384), (float*)(smem + 16384 + 32768));
    } else if (f < 160) {               // Q-proj: 4 by x 8 b
        const int f2 = f - 128;
        gemm_body<128, 256, true, 1>(
            G, WqT, Qb, T_, P_, DG_, (long)T_ * DG_, 0, (long)T_ * P_,
            0.0625f, nullptr, nullptr, 0, f2 & 3, f2 >> 2,
            (short*)smem, (short*)(smem + 16384), (float*)(smem + 16384 + 32768));
    } else {
        const int f3 = f - 160;         // 32 x 16 x 8
        const int tx = f3 & 31, ty = (f3 >> 5) & 15, b = f3 >> 9;
        transpose64_body(H + (long)b * L_ * DH_, Ht + (long)b * DH_ * L_,
                         L_, DH_, tx * 64, ty * 64, (float*)smem);
    }
}

// Phase C: e = exp(Q K^T) (mask->0) + row partial sums. 1024 blocks.
__global__ __launch_bounds__(256) void k_qk(
    const short* __restrict__ Qb, const short* __restrict__ Kb,
    short* __restrict__ alpha, const unsigned char* __restrict__ mask,
    float* __restrict__ psum)
{
    __shared__ __align__(16) short As[128 * 64];
    __shared__ __align__(16) short Bs[64 * 64];
    const int gx = gridDim.x, gy = gridDim.y;
    const int nwg = gx * gy * (int)gridDim.z;
    int flat = blockIdx.x + gx * (blockIdx.y + gy * blockIdx.z);
    flat = (flat & 7) * (nwg >> 3) + (flat >> 3);
    const int bx = flat % gx, by = (flat / gx) % gy, b = flat / (gx * gy);
    gemm_body<128, 64, false, 2>(
        Qb, Kb, alpha, T_, L_, P_, (long)T_ * P_, (long)L_ * P_, (long)T_ * L_,
        1.0f, mask, psum, bx, by, b, As, Bs, nullptr);
}

// Phase D: Z = (e @ H) / rowsum(e). 512 blocks.
__global__ __launch_bounds__(256) void k_pv(
    const short* __restrict__ alpha, const short* __restrict__ Ht,
    float* __restrict__ Z, float* __restrict__ psum)
{
    __shared__ __align__(16) short As[128 * 64];
    __shared__ __align__(16) short Bs[64 * 64];
    __shared__ float invL[128];
    const int gx = gridDim.x, gy = gridDim.y;
    const int nwg = gx * gy * (int)gridDim.z;
    int flat = blockIdx.x + gx * (blockIdx.y + gy * blockIdx.z);
    flat = (flat & 7) * (nwg >> 3) + (flat >> 3);
    const int bx = flat % gx, by = (flat / gx) % gy, b = flat / (gx * gy);
    gemm_body<128, 64, false, 3>(
        alpha, Ht, Z, T_, DH_, L_, (long)T_ * L_, (long)DH_ * L_, (long)T_ * DH_,
        1.0f, nullptr, psum, bx, by, b, As, Bs, invL);
}

extern "C" void kernel_launch(void* const* d_in, const int* in_sizes, int n_in,
                              void* d_out, int out_size, void* d_ws, size_t ws_size,
                              hipStream_t stream)
{
    const float* H  = (const float*)d_in[0];
    const float* G  = (const float*)d_in[1];
    const float* Wk = (const float*)d_in[2];
    const float* Wq = (const float*)d_in[3];
    const unsigned char* mask = (const unsigned char*)d_in[4];
    float* Z = (float*)d_out;

    char* ws = (char*)d_ws;
    const long OFF_WKT   = 0;                       // 256x1024 bf16 = 512 KB
    const long OFF_WQT   = 524288;                  // 256x768  bf16 = 384 KB
    const long OFF_HT    = 917504;                  // 8x1024x2048 bf16 = 32 MB
    const long OFF_KB    = OFF_HT + 33554432;       // 8x2048x256 bf16 = 8 MB
    const long OFF_QB    = OFF_KB + 8388608;        // 8x512x256 bf16 = 2 MB
    const long OFF_ALPHA = OFF_QB + 2097152;        // 8x512x2048 bf16 = 16 MB
    const long OFF_PSUM  = OFF_ALPHA + 16777216;    // 8x512x32 f32 = 512 KB
    short* WkT   = (short*)(ws + OFF_WKT);
    short* WqT   = (short*)(ws + OFF_WQT);
    short* Ht    = (short*)(ws + OFF_HT);
    short* Kb    = (short*)(ws + OFF_KB);
    short* Qb    = (short*)(ws + OFF_QB);
    short* alpha = (short*)(ws + OFF_ALPHA);        // unnormalized e = exp(logit)
    float* psum  = (float*)(ws + OFF_PSUM);

    // A: weight transposes (448 blocks)
    k_weights<<<dim3(448), 256, 0, stream>>>(Wk, WkT, Wq, WqT);

    // B: K-proj + Q-proj + Ht transpose, one launch (4256 blocks)
    k_phaseB<<<dim3(4256), 256, 0, stream>>>(H, G, WkT, WqT, Kb, Qb, Ht);

    // C: QK + exp + partial sums
    k_qk<<<dim3(L_/64, T_/128, B_), 256, 0, stream>>>(Qb, Kb, alpha, mask, psum);

    // D: PV + normalize
    k_pv<<<dim3(DH_/64, T_/128, B_), 256, 0, stream>>>(alpha, Ht, Z, psum);
}

// Round 7
// 82.477 us; speedup vs baseline: 1.1328x; 1.1328x over previous
//
#include <hip/hip_runtime.h>
#include <hip/hip_bf16.h>

typedef __attribute__((ext_vector_type(8))) short short8;
typedef __attribute__((ext_vector_type(4))) float f32x4;

#define B_  8
#define L_  2048
#define T_  512
#define DH_ 1024
#define DG_ 768
#define P_  256

__device__ __forceinline__ short f2bf(float x) {
    union { float f; unsigned u; } v; v.f = x;
    unsigned r = v.u + 0x7fffu + ((v.u >> 16) & 1u);
    return (short)(r >> 16);
}

typedef __attribute__((address_space(1))) const void av1_t;
typedef __attribute__((address_space(3))) void av3_t;
__device__ __forceinline__ void gl16(const void* g, void* l) {
    __builtin_amdgcn_global_load_lds((av1_t*)g, (av3_t*)l, 16, 0, 0);
}

// ---------------- shared GEMM body ----------------
// C[M,N] = A[M,K] * B[N,K]^T, 4 waves (2x2), BK=64, gl16 staging for bf16,
// XOR-swizzled LDS. As: BM*64 shorts, Bs: BN*64 shorts, invL: BM floats.
// EPI: 1 = bf16 C*cscale
//      2 = QK: e=mask?0:exp(C); bf16 e + per-row partial sums psum[row][32]
//      3 = PV: f32 C * (1/sum(psum row))
// WRT: K-proj fusion — while the f32->bf16 A-tile (32 l x 64 dh) sits in LDS,
//      also emit its transpose to Htw[b][dh][l] (64B segments per dh row).
template<int BM, int BN, bool AF32, int EPI, bool WRT>
__device__ __forceinline__ void gemm_body(
    const void* __restrict__ Ap, const short* __restrict__ Bp,
    void* __restrict__ Cp, int M, int N, int K, long sA, long sB, long sC,
    float cscale, const unsigned char* __restrict__ mask,
    float* __restrict__ psum, int bx, int by, int b,
    short* As, short* Bs, float* invL, short* __restrict__ Htw)
{
    constexpr int WM = BM / 2, WN = BN / 2, FM = WM / 16, FN = WN / 16;
    const int m0 = by * BM, n0 = bx * BN;

    const int t = threadIdx.x, w = t >> 6, l = t & 63;
    const int wm = w >> 1, wn = w & 1, rl = l & 15, kg = l >> 4;

    const int srow = t >> 3;
    const int schunk = t & 7;
    const int gchunk = schunk ^ (srow & 7);

    const short* Bg0 = Bp + (long)b * sB + (long)(n0 + srow) * K + gchunk * 8;
    char* AsP = (char*)As + t * 16;
    char* BsP = (char*)Bs + t * 16;

    const int ch0 = ((0 | kg) ^ (rl & 7)) * 16;
    const int ch1 = ((4 | kg) ^ (rl & 7)) * 16;

    if constexpr (EPI == 3) {   // denominators: overlap with first staging
        if (t < BM) {
            const float* pp = psum + ((long)b * M + m0 + t) * 32;
            float s = 0.f;
            #pragma unroll
            for (int j = 0; j < 32; j++) s += pp[j];
            invL[t] = 1.0f / s;
        }
    }

    f32x4 acc[FM][FN];
    #pragma unroll
    for (int mi = 0; mi < FM; mi++)
        #pragma unroll
        for (int ni = 0; ni < FN; ni++)
            acc[mi][ni] = (f32x4){0.f, 0.f, 0.f, 0.f};

    for (int k0 = 0; k0 < K; k0 += 64) {
        if (AF32) {
            #pragma unroll
            for (int j = 0; j < BM / 32; j++) {
                const float* ag = (const float*)Ap + (long)b * sA +
                                  (long)(m0 + j * 32 + srow) * K + k0 + schunk * 8;
                float4 v0 = *(const float4*)ag;
                float4 v1 = *(const float4*)(ag + 4);
                short8 sv;
                sv[0]=f2bf(v0.x); sv[1]=f2bf(v0.y); sv[2]=f2bf(v0.z); sv[3]=f2bf(v0.w);
                sv[4]=f2bf(v1.x); sv[5]=f2bf(v1.y); sv[6]=f2bf(v1.z); sv[7]=f2bf(v1.w);
                *(short8*)&As[(j * 32 + srow) * 64 + (schunk ^ (srow & 7)) * 8] = sv;
            }
        } else {
            const short* Ag0 = (const short*)Ap + (long)b * sA +
                               (long)(m0 + srow) * K + k0 + gchunk * 8;
            #pragma unroll
            for (int j = 0; j < BM / 32; j++)
                gl16(Ag0 + (long)j * 32 * K, AsP + j * 4096);
        }
        #pragma unroll
        for (int j = 0; j < BN / 32; j++)
            gl16(Bg0 + k0 + (long)j * 32 * K, BsP + j * 4096);
        __syncthreads();

        #pragma unroll
        for (int kh = 0; kh < 2; kh++) {
            const int ch = kh ? ch1 : ch0;
            short8 a[FM], bb[FN];
            #pragma unroll
            for (int mi = 0; mi < FM; mi++)
                a[mi] = *(short8*)((char*)&As[(wm * WM + mi * 16 + rl) * 64] + ch);
            #pragma unroll
            for (int ni = 0; ni < FN; ni++)
                bb[ni] = *(short8*)((char*)&Bs[(wn * WN + ni * 16 + rl) * 64] + ch);
            #pragma unroll
            for (int mi = 0; mi < FM; mi++)
                #pragma unroll
                for (int ni = 0; ni < FN; ni++)
                    acc[mi][ni] = __builtin_amdgcn_mfma_f32_16x16x32_bf16(
                        a[mi], bb[ni], acc[mi][ni], 0, 0, 0);
        }

        if constexpr (WRT) {
            // As (32 l x 64 dh, swizzled) -> Htw[b][k0+dhl][m0 + q*8 ..]
            static_assert(!WRT || BM == 32, "WRT path assumes BM==32");
            const int dhl = t >> 2, q = t & 3;
            short8 hv;
            #pragma unroll
            for (int j = 0; j < 8; j++) {
                const int ll = q * 8 + j;
                hv[j] = As[ll * 64 + (((dhl >> 3) ^ j) << 3) + (dhl & 7)];
            }
            *(short8*)(Htw + (long)b * DH_ * L_ + (long)(k0 + dhl) * L_ +
                       m0 + q * 8) = hv;
        }
        __syncthreads();
    }

    const int rowb = m0 + wm * WM + kg * 4;

    if constexpr (EPI == 2) {
        float* psL = (float*)As;  // [2][BM]
        float pr[FM][4];
        #pragma unroll
        for (int mi = 0; mi < FM; mi++)
            #pragma unroll
            for (int i = 0; i < 4; i++) pr[mi][i] = 0.f;
        #pragma unroll
        for (int mi = 0; mi < FM; mi++)
            #pragma unroll
            for (int ni = 0; ni < FN; ni++) {
                const int n = n0 + wn * WN + ni * 16 + rl;
                const bool mk = mask[(long)b * N + n] != 0;
                #pragma unroll
                for (int i = 0; i < 4; i++) {
                    const float e = mk ? 0.f : __expf(acc[mi][ni][i]);
                    ((short*)Cp)[(long)b * sC + (long)(rowb + mi * 16 + i) * N + n] = f2bf(e);
                    pr[mi][i] += e;
                }
            }
        #pragma unroll
        for (int off = 1; off < 16; off <<= 1)
            #pragma unroll
            for (int mi = 0; mi < FM; mi++)
                #pragma unroll
                for (int i = 0; i < 4; i++)
                    pr[mi][i] += __shfl_xor(pr[mi][i], off);
        if (rl == 0) {
            #pragma unroll
            for (int mi = 0; mi < FM; mi++)
                #pragma unroll
                for (int i = 0; i < 4; i++)
                    psL[wn * BM + wm * WM + mi * 16 + kg * 4 + i] = pr[mi][i];
        }
        __syncthreads();
        if (t < BM)
            psum[((long)b * M + m0 + t) * 32 + bx] = psL[t] + psL[BM + t];
        return;
    }

    #pragma unroll
    for (int mi = 0; mi < FM; mi++)
        #pragma unroll
        for (int ni = 0; ni < FN; ni++) {
            const int n = n0 + wn * WN + ni * 16 + rl;
            #pragma unroll
            for (int i = 0; i < 4; i++) {
                const long idx = (long)b * sC + (long)(rowb + mi * 16 + i) * N + n;
                if constexpr (EPI == 1)
                    ((short*)Cp)[idx] = f2bf(acc[mi][ni][i] * cscale);
                else  // EPI == 3
                    ((float*)Cp)[idx] = acc[mi][ni][i] *
                                        invL[wm * WM + mi * 16 + kg * 4 + i];
            }
        }
}

// ---------------- transpose body (weights only) ----------------
__device__ __forceinline__ void transpose32_body(
    const float* __restrict__ s, short* __restrict__ d,
    int R, int C, int r0, int c0, float* tile /*32x33*/)
{
    const int x = threadIdx.x & 31, y = threadIdx.x >> 5;
    #pragma unroll
    for (int i = 0; i < 32; i += 8)
        tile[(y + i) * 33 + x] = s[(long)(r0 + y + i) * C + (c0 + x)];
    __syncthreads();
    #pragma unroll
    for (int i = 0; i < 32; i += 8)
        d[(long)(c0 + y + i) * R + (r0 + x)] = f2bf(tile[x * 33 + y + i]);
}

// ---------------- kernels ----------------
// Phase A: both weight transposes. blocks: Wk 32x8=256, Wq 24x8=192.
__global__ __launch_bounds__(256) void k_weights(
    const float* __restrict__ Wk, short* __restrict__ WkT,
    const float* __restrict__ Wq, short* __restrict__ WqT)
{
    __shared__ float tile[32 * 33];
    const int f = blockIdx.x;
    if (f < 256) {
        transpose32_body(Wk, WkT, DH_, P_, (f & 31) * 32, (f >> 5) * 32, tile);
    } else {
        const int f2 = f - 256;
        transpose32_body(Wq, WqT, DG_, P_, (f2 % 24) * 32, (f2 / 24) * 32, tile);
    }
}

// Phase B: K-proj with fused Ht emission (512 blocks) + Q-proj (128 blocks).
// 32x256 tiles: H and G read exactly once; Ht written from the staged LDS
// tile between the existing barriers (no extra sync).
__global__ __launch_bounds__(256) void k_phaseB(
    const float* __restrict__ H, const float* __restrict__ G,
    const short* __restrict__ WkT, const short* __restrict__ WqT,
    short* __restrict__ Kb, short* __restrict__ Qb, short* __restrict__ Ht)
{
    __shared__ __align__(16) char smem[4096 + 32768 + 128];
    const int f = blockIdx.x;
    if (f < 512) {
        gemm_body<32, 256, true, 1, true>(
            H, WkT, Kb, L_, P_, DH_, (long)L_ * DH_, 0, (long)L_ * P_,
            1.0f, nullptr, nullptr, 0, f & 63, f >> 6,
            (short*)smem, (short*)(smem + 4096), (float*)(smem + 4096 + 32768), Ht);
    } else {
        const int f2 = f - 512;
        gemm_body<32, 256, true, 1, false>(
            G, WqT, Qb, T_, P_, DG_, (long)T_ * DG_, 0, (long)T_ * P_,
            0.0625f, nullptr, nullptr, 0, f2 & 15, f2 >> 4,
            (short*)smem, (short*)(smem + 4096), (float*)(smem + 4096 + 32768), nullptr);
    }
}

// Phase C: e = exp(Q K^T) (mask->0) + row partial sums. 1024 blocks.
__global__ __launch_bounds__(256) void k_qk(
    const short* __restrict__ Qb, const short* __restrict__ Kb,
    short* __restrict__ alpha, const unsigned char* __restrict__ mask,
    float* __restrict__ psum)
{
    __shared__ __align__(16) short As[128 * 64];
    __shared__ __align__(16) short Bs[64 * 64];
    const int gx = gridDim.x, gy = gridDim.y;
    const int nwg = gx * gy * (int)gridDim.z;
    int flat = blockIdx.x + gx * (blockIdx.y + gy * blockIdx.z);
    flat = (flat & 7) * (nwg >> 3) + (flat >> 3);
    const int bx = flat % gx, by = (flat / gx) % gy, b = flat / (gx * gy);
    gemm_body<128, 64, false, 2, false>(
        Qb, Kb, alpha, T_, L_, P_, (long)T_ * P_, (long)L_ * P_, (long)T_ * L_,
        1.0f, mask, psum, bx, by, b, As, Bs, nullptr, nullptr);
}

// Phase D: Z = (e @ H) / rowsum(e). 512 blocks.
__global__ __launch_bounds__(256) void k_pv(
    const short* __restrict__ alpha, const short* __restrict__ Ht,
    float* __restrict__ Z, float* __restrict__ psum)
{
    __shared__ __align__(16) short As[128 * 64];
    __shared__ __align__(16) short Bs[64 * 64];
    __shared__ float invL[128];
    const int gx = gridDim.x, gy = gridDim.y;
    const int nwg = gx * gy * (int)gridDim.z;
    int flat = blockIdx.x + gx * (blockIdx.y + gy * blockIdx.z);
    flat = (flat & 7) * (nwg >> 3) + (flat >> 3);
    const int bx = flat % gx, by = (flat / gx) % gy, b = flat / (gx * gy);
    gemm_body<128, 64, false, 3, false>(
        alpha, Ht, Z, T_, DH_, L_, (long)T_ * L_, (long)DH_ * L_, (long)T_ * DH_,
        1.0f, nullptr, psum, bx, by, b, As, Bs, invL, nullptr);
}

extern "C" void kernel_launch(void* const* d_in, const int* in_sizes, int n_in,
                              void* d_out, int out_size, void* d_ws, size_t ws_size,
                              hipStream_t stream)
{
    const float* H  = (const float*)d_in[0];
    const float* G  = (const float*)d_in[1];
    const float* Wk = (const float*)d_in[2];
    const float* Wq = (const float*)d_in[3];
    const unsigned char* mask = (const unsigned char*)d_in[4];
    float* Z = (float*)d_out;

    char* ws = (char*)d_ws;
    const long OFF_WKT   = 0;                       // 256x1024 bf16 = 512 KB
    const long OFF_WQT   = 524288;                  // 256x768  bf16 = 384 KB
    const long OFF_HT    = 917504;                  // 8x1024x2048 bf16 = 32 MB
    const long OFF_KB    = OFF_HT + 33554432;       // 8x2048x256 bf16 = 8 MB
    const long OFF_QB    = OFF_KB + 8388608;        // 8x512x256 bf16 = 2 MB
    const long OFF_ALPHA = OFF_QB + 2097152;        // 8x512x2048 bf16 = 16 MB
    const long OFF_PSUM  = OFF_ALPHA + 16777216;    // 8x512x32 f32 = 512 KB
    short* WkT   = (short*)(ws + OFF_WKT);
    short* WqT   = (short*)(ws + OFF_WQT);
    short* Ht    = (short*)(ws + OFF_HT);
    short* Kb    = (short*)(ws + OFF_KB);
    short* Qb    = (short*)(ws + OFF_QB);
    short* alpha = (short*)(ws + OFF_ALPHA);        // unnormalized e = exp(logit)
    float* psum  = (float*)(ws + OFF_PSUM);

    // A: weight transposes (448 blocks)
    k_weights<<<dim3(448), 256, 0, stream>>>(Wk, WkT, Wq, WqT);

    // B: K-proj (+fused Ht) + Q-proj, one launch (640 blocks, 2.5/CU)
    k_phaseB<<<dim3(640), 256, 0, stream>>>(H, G, WkT, WqT, Kb, Qb, Ht);

    // C: QK + exp + partial sums
    k_qk<<<dim3(L_/64, T_/128, B_), 256, 0, stream>>>(Qb, Kb, alpha, mask, psum);

    // D: PV + normalize
    k_pv<<<dim3(DH_/64, T_/128, B_), 256, 0, stream>>>(alpha, Ht, Z, psum);
}